// Round 7
// baseline (145.447 us; speedup 1.0000x reference)
//
#include <hip/hip_runtime.h>
#include <math.h>

#define NN 512
#define FF 64
#define HH 4

// ---------------- ws layout (floats) ----------------
// dinv : [512]               off 0
// cvec : [512]               off 512
// T    : [B*H*N]   = 8192    off 1024
// q_t  : [B*H*N*F] = 2097152 off 9216
// k_t  : [B*H*N*F] = 2097152 off 2106368   (same [bh][j][f] layout as q_t)

// S1: q+k projection (512 blocks x 512 thr, 4 rows; threads 0-255 = q cols,
//     256-511 = k cols). No LDS: x rows are wave-uniform -> s_load; W
//     prefetched to 64 VGPRs (64 loads in flight).
//     Side jobs (no barrier needed): wave0 -> dinv[blk]; wave1 -> zero T
//     slice; wave2 -> zero cvec[blk].
__global__ __launch_bounds__(512) void k_s1(const float* __restrict__ x,
                                            const float* __restrict__ Wq,
                                            const float* __restrict__ bq,
                                            const float* __restrict__ Wk,
                                            const float* __restrict__ bk,
                                            const float* __restrict__ adj,
                                            float* __restrict__ q_t,
                                            float* __restrict__ k_t,
                                            float* __restrict__ dinv,
                                            float* __restrict__ T,
                                            float* __restrict__ cvec) {
    int blk = blockIdx.x, tid = threadIdx.x;
    int wave = tid >> 6, lane = tid & 63;
    int b = blk >> 7, itile = blk & 127;
    int i0 = itile * 4;

    if (wave == 0) {
        float acc = 0.f;
#pragma unroll
        for (int k = 0; k < 8; ++k) acc += adj[(long)blk * NN + k * 64 + lane];
        for (int o = 32; o > 0; o >>= 1) acc += __shfl_xor(acc, o);
        if (lane == 0) dinv[blk] = 1.0f / sqrtf(acc + 1.0f);
    } else if (wave == 1) {
        if (lane < 16) T[blk * 16 + lane] = 0.f;
    } else if (wave == 2) {
        if (lane == 0) cvec[blk] = 0.f;
    }

    int isK = tid >> 8, col = tid & 255;
    const float* W = isK ? Wk : Wq;
    float wv[64];
#pragma unroll
    for (int cc = 0; cc < 64; ++cc) wv[cc] = W[cc * 256 + col];

    float bv = (isK ? bk : bq)[col];
    float a0 = bv, a1 = bv, a2 = bv, a3 = bv;
    const float* xr = x + ((long)b * NN + i0) * FF;   // wave-uniform -> s_load
#pragma unroll
    for (int cc = 0; cc < 64; ++cc) {
        float w = wv[cc];
        a0 = fmaf(xr[cc], w, a0);
        a1 = fmaf(xr[64 + cc], w, a1);
        a2 = fmaf(xr[128 + cc], w, a2);
        a3 = fmaf(xr[192 + cc], w, a3);
    }
    int h = col >> 6, f = col & 63;
    float* dst = (isK ? k_t : q_t) + ((long)(b * HH + h) * NN + i0) * FF + f;
    dst[0] = a0; dst[FF] = a1; dst[2 * FF] = a2; dst[3 * FF] = a3;
}

// S2: scores -> softmax -> noradj weighting -> atomicAdd into T (+cvec).
//     512 blocks x 512 thr; 16 i-rows per block, one j per thread.
//     K-row prefetched as 16 float4 vector loads; q read via wave-uniform
//     global loads (scalar pipe). No q LDS.
__global__ __launch_bounds__(512) void k_s2(const float* __restrict__ q_t,
                                            const float* __restrict__ k_t,
                                            const float* __restrict__ adj,
                                            const float* __restrict__ dinv,
                                            float* __restrict__ T,
                                            float* __restrict__ cvec) {
    __shared__ float red[16][8];
    __shared__ float red2[16][8];
    int blk = blockIdx.x, tid = threadIdx.x;
    int itile = blk & 31, h = (blk >> 5) & 3, b = blk >> 7;
    int bh = b * HH + h, i0 = itile * 16;
    int wv_ = tid >> 6, lane = tid & 63;
    int j = tid;

    float4 kv[16];
    const float4* kb4 = (const float4*)(k_t + ((long)bh * NN + j) * FF);
#pragma unroll
    for (int u = 0; u < 16; ++u) kv[u] = kb4[u];   // 16 loads in flight

    const float4* qb4 = (const float4*)(q_t + ((long)bh * NN + i0) * FF);
    float s[16];
#pragma unroll
    for (int r = 0; r < 16; ++r) {
        float acc = 0.f;
#pragma unroll
        for (int u = 0; u < 16; ++u) {
            float4 qv = qb4[r * 16 + u];           // uniform -> s_load_dwordx4
            acc = fmaf(qv.x, kv[u].x, acc);
            acc = fmaf(qv.y, kv[u].y, acc);
            acc = fmaf(qv.z, kv[u].z, acc);
            acc = fmaf(qv.w, kv[u].w, acc);
        }
        s[r] = acc;
    }

    const float scale = 0.125f;   // 1/sqrt(64)
#pragma unroll
    for (int r = 0; r < 16; ++r) {
        float v = s[r];
        for (int o = 32; o > 0; o >>= 1) v = fmaxf(v, __shfl_xor(v, o));
        if (lane == 0) red[r][wv_] = v;
    }
    __syncthreads();
    float m[16];
#pragma unroll
    for (int r = 0; r < 16; ++r) {
        float v = red[r][0];
#pragma unroll
        for (int w = 1; w < 8; ++w) v = fmaxf(v, red[r][w]);
        m[r] = v;
    }
#pragma unroll
    for (int r = 0; r < 16; ++r) {
        s[r] = expf((s[r] - m[r]) * scale);
        float v = s[r];
        for (int o = 32; o > 0; o >>= 1) v += __shfl_xor(v, o);
        if (lane == 0) red2[r][wv_] = v;
    }
    __syncthreads();

    float av[16];
#pragma unroll
    for (int r = 0; r < 16; ++r) av[r] = adj[(long)(i0 + r) * NN + j];

    float dj = dinv[j];
    float pw = 0.f, cw = 0.f;
#pragma unroll
    for (int r = 0; r < 16; ++r) {
        float z = red2[r][0];
#pragma unroll
        for (int w = 1; w < 8; ++w) z += red2[r][w];
        float Zi = 1.0f / z;
        int gi = i0 + r;
        float di = dinv[gi];                       // uniform -> s_load
        float a = av[r] + (gi == j ? 1.f : 0.f);
        float t = di * a;
        pw = fmaf(t, s[r] * Zi, pw);
        cw += t;
    }
    atomicAdd(&T[bh * NN + j], pw * dj);
    if (bh == 0) atomicAdd(&cvec[j], cw);
}

// S3: fused sxd + SpMM + FC + relu. 512 blocks x 256 thr, 4 rows each,
//     4-way j-split. All per-j scalars (dinv/cvec/T/adj) read via
//     wave-uniform global loads (scalar pipe); x per-lane, batched 8 deep.
__global__ __launch_bounds__(256) void k_s3(const float* __restrict__ x,
                                            const float* __restrict__ T,
                                            const float* __restrict__ Wlin,
                                            const float* __restrict__ blin,
                                            const float* __restrict__ cvec,
                                            const float* __restrict__ adj,
                                            const float* __restrict__ dinv,
                                            const float* __restrict__ Wfc,
                                            const float* __restrict__ bfc,
                                            float* __restrict__ out) {
    __shared__ float part[4][4][64];
    __shared__ float m_lds[4][64];
    int blk = blockIdx.x, tid = threadIdx.x;
    int b = blk >> 7, itile = blk & 127;
    int i0 = itile * 4;
    int f = tid & 63, jc = tid >> 6;
    int jb = jc * 128;

    float blf = blin[f];
    float4 wl = make_float4(Wlin[f], Wlin[64 + f], Wlin[128 + f], Wlin[192 + f]);
    const float* xb = x + (long)b * NN * FF + f;
    const float* Tb = T + (long)b * HH * NN;
    float a0 = 0.f, a1 = 0.f, a2 = 0.f, a3 = 0.f;

    for (int j = jb; j < jb + 128; j += 8) {
        float xv[8];
#pragma unroll
        for (int u = 0; u < 8; ++u) xv[u] = xb[(long)(j + u) * FF];
#pragma unroll
        for (int u = 0; u < 8; ++u) {
            int jj = j + u;
            float dj = dinv[jj];                   // uniform
            float cj = dj * dj * cvec[jj];
            float t0 = dj * Tb[jj];
            float t1 = dj * Tb[NN + jj];
            float t2 = dj * Tb[2 * NN + jj];
            float t3 = dj * Tb[3 * NN + jj];
            float S = blf * cj;
            S = fmaf(wl.x, t0, S);
            S = fmaf(wl.y, t1, S);
            S = fmaf(wl.z, t2, S);
            S = fmaf(wl.w, t3, S);
            float sx = xv[u] * S;
            float d0 = adj[(long)(i0 + 0) * NN + jj] + (i0 + 0 == jj ? 1.f : 0.f);
            float d1 = adj[(long)(i0 + 1) * NN + jj] + (i0 + 1 == jj ? 1.f : 0.f);
            float d2 = adj[(long)(i0 + 2) * NN + jj] + (i0 + 2 == jj ? 1.f : 0.f);
            float d3 = adj[(long)(i0 + 3) * NN + jj] + (i0 + 3 == jj ? 1.f : 0.f);
            a0 = fmaf(d0, sx, a0);
            a1 = fmaf(d1, sx, a1);
            a2 = fmaf(d2, sx, a2);
            a3 = fmaf(d3, sx, a3);
        }
    }
    part[jc][0][f] = a0; part[jc][1][f] = a1;
    part[jc][2][f] = a2; part[jc][3][f] = a3;
    __syncthreads();
    // each wave combines + FCs its own row r = jc
    m_lds[jc][f] = (part[0][jc][f] + part[1][jc][f] + part[2][jc][f] + part[3][jc][f])
                   * dinv[i0 + jc];
    __syncthreads();
    float o = bfc[f];
#pragma unroll
    for (int cc = 0; cc < 64; ++cc)
        o = fmaf(m_lds[jc][cc], Wfc[cc * FF + f], o);   // m_lds uniform bcast
    out[((long)b * NN + i0 + jc) * FF + f] = fmaxf(o, 0.f);
}

extern "C" void kernel_launch(void* const* d_in, const int* in_sizes, int n_in,
                              void* d_out, int out_size, void* d_ws, size_t ws_size,
                              hipStream_t stream) {
    const float* x    = (const float*)d_in[0];
    const float* adj  = (const float*)d_in[1];
    const float* Wq   = (const float*)d_in[2];
    const float* bq   = (const float*)d_in[3];
    const float* Wk   = (const float*)d_in[4];
    const float* bk   = (const float*)d_in[5];
    const float* Wlin = (const float*)d_in[6];
    const float* blin = (const float*)d_in[7];
    const float* Wfc  = (const float*)d_in[8];
    const float* bfc  = (const float*)d_in[9];
    float* out = (float*)d_out;

    float* ws   = (float*)d_ws;
    float* dinv = ws;                 // 512
    float* cvec = ws + 512;           // 512
    float* T    = ws + 1024;          // 8192
    float* q_t  = ws + 9216;          // 2097152
    float* k_t  = ws + 2106368;       // 2097152

    k_s1<<<dim3(512), dim3(512), 0, stream>>>(x, Wq, bq, Wk, bk, adj, q_t, k_t, dinv, T, cvec);
    k_s2<<<dim3(512), dim3(512), 0, stream>>>(q_t, k_t, adj, dinv, T, cvec);
    k_s3<<<dim3(512), dim3(256), 0, stream>>>(x, T, Wlin, blin, cvec, adj, dinv, Wfc, bfc, out);
}

// Round 8
// 120.945 us; speedup vs baseline: 1.2026x; 1.2026x over previous
//
#include <hip/hip_runtime.h>
#include <math.h>

#define NN 512
#define FF 64
#define HH 4

// ---------------- ws layout (floats) ----------------
// dinv : [512]               off 0
// cvec : [512]               off 512
// T    : [B*H*N]   = 8192    off 1024
// q_t  : [B*H*N*F] = 2097152 off 9216
// k_t  : [B*H*N*F] = 2097152 off 2106368   ([bh][j][f], same as q_t)

// S1 (R4 verbatim): q/k projection, 4-row tiles, q XOR k per block.
__global__ __launch_bounds__(256) void k_s1(const float* __restrict__ x,
                                            const float* __restrict__ Wq,
                                            const float* __restrict__ bq,
                                            const float* __restrict__ Wk,
                                            const float* __restrict__ bk,
                                            const float* __restrict__ adj,
                                            float* __restrict__ q_t,
                                            float* __restrict__ k_t,
                                            float* __restrict__ dinv,
                                            float* __restrict__ T,
                                            float* __restrict__ cvec) {
    __shared__ float x_lds[4][64];
    int blk = blockIdx.x, tid = threadIdx.x;
    int wave = tid >> 6, lane = tid & 63;

    if (blk < 512 && wave == 0) {
        float acc = 0.f;
#pragma unroll
        for (int k = 0; k < 8; ++k) acc += adj[(long)blk * NN + k * 64 + lane];
        for (int o = 32; o > 0; o >>= 1) acc += __shfl_xor(acc, o);
        if (lane == 0) dinv[blk] = 1.0f / sqrtf(acc + 1.0f);
    }
    if (blk < 128 && wave == 1) T[blk * 64 + lane] = 0.f;
    if (blk < 8 && wave == 2) cvec[blk * 64 + lane] = 0.f;

    int b = blk >> 8, rest = blk & 255, isK = rest >> 7, itile = rest & 127;
    int i0 = itile * 4;
    x_lds[tid >> 6][tid & 63] = x[((long)b * NN + i0 + (tid >> 6)) * FF + (tid & 63)];
    __syncthreads();
    const float* W = isK ? Wk : Wq;
    float bv = (isK ? bk : bq)[tid];
    float a0 = bv, a1 = bv, a2 = bv, a3 = bv;
    for (int cc = 0; cc < 64; ++cc) {
        float w = W[cc * 256 + tid];
        a0 = fmaf(x_lds[0][cc], w, a0);
        a1 = fmaf(x_lds[1][cc], w, a1);
        a2 = fmaf(x_lds[2][cc], w, a2);
        a3 = fmaf(x_lds[3][cc], w, a3);
    }
    int h = tid >> 6, f = tid & 63;
    float* dst = (isK ? k_t : q_t) + ((long)(b * HH + h) * NN + i0) * FF + f;
    dst[0] = a0; dst[FF] = a1; dst[2 * FF] = a2; dst[3 * FF] = a3;
}

// S2: register-tiled QK^T GEMM + softmax + noradj weighting -> T, cvec.
// 512 blocks (bh x 32 i-tiles of 16 rows), 512 threads.
// Thread (ig=tid&7, jg=tid>>3) owns acc[2][8]: rows i0+ig*2+ii, cols jg*8+jj.
__global__ __launch_bounds__(512) void k_s2(const float* __restrict__ q_t,
                                            const float* __restrict__ k_t,
                                            const float* __restrict__ adj,
                                            const float* __restrict__ dinv,
                                            float* __restrict__ T,
                                            float* __restrict__ cvec) {
    __shared__ float ql[16 * 68];      // q tile, padded rows (16B-aligned)
    __shared__ float kl[512 * 16];     // k chunk (xor-swizzled f4 slots); reused as adj tile [16][512]
    __shared__ float redm[8][16];
    __shared__ float redz[8][16];
    int blk = blockIdx.x, tid = threadIdx.x;
    int bh = blk >> 5, itile = blk & 31;
    int i0 = itile * 16;
    int wv = tid >> 6;
    int ig = tid & 7, jg = tid >> 3;

    if (tid < 256) {
        int r = tid >> 4, c4 = tid & 15;
        *(float4*)&ql[r * 68 + c4 * 4] =
            *(const float4*)(q_t + ((long)bh * NN + i0 + r) * FF + c4 * 4);
    }

    float acc[2][8];
#pragma unroll
    for (int ii = 0; ii < 2; ++ii)
#pragma unroll
        for (int jj = 0; jj < 8; ++jj) acc[ii][jj] = 0.f;

    const float* kb = k_t + (long)bh * NN * FF;
#pragma unroll
    for (int cc = 0; cc < 4; ++cc) {
        // stage k chunk: all 512 rows, 16 cols, 4 f4/thread, swizzled slot
#pragma unroll
        for (int w = 0; w < 4; ++w) {
            int v = w * 512 + tid;
            int row = v >> 2, c4 = v & 3;
            int slot = c4 ^ ((row >> 3) & 3);
            *(float4*)&kl[row * 16 + slot * 4] =
                *(const float4*)(kb + (long)row * FF + cc * 16 + c4 * 4);
        }
        __syncthreads();
#pragma unroll
        for (int k4 = 0; k4 < 4; ++k4) {
            float4 qf[2], kf[8];
#pragma unroll
            for (int ii = 0; ii < 2; ++ii)
                qf[ii] = *(const float4*)&ql[(ig * 2 + ii) * 68 + cc * 16 + k4 * 4];
#pragma unroll
            for (int jj = 0; jj < 8; ++jj) {
                int j = jg * 8 + jj;
                int slot = k4 ^ ((j >> 3) & 3);
                kf[jj] = *(const float4*)&kl[j * 16 + slot * 4];
            }
#pragma unroll
            for (int ii = 0; ii < 2; ++ii)
#pragma unroll
                for (int jj = 0; jj < 8; ++jj) {
                    acc[ii][jj] = fmaf(qf[ii].x, kf[jj].x, acc[ii][jj]);
                    acc[ii][jj] = fmaf(qf[ii].y, kf[jj].y, acc[ii][jj]);
                    acc[ii][jj] = fmaf(qf[ii].z, kf[jj].z, acc[ii][jj]);
                    acc[ii][jj] = fmaf(qf[ii].w, kf[jj].w, acc[ii][jj]);
                }
        }
        __syncthreads();
    }

    // stage adj tile into kl (free to overwrite now); guarded by next barrier
#pragma unroll
    for (int w = 0; w < 4; ++w) {
        int v = w * 512 + tid;
        int r = v >> 7, c4 = v & 127;
        *(float4*)&kl[r * 512 + c4 * 4] =
            *(const float4*)(adj + (long)(i0 + r) * NN + c4 * 4);
    }

    // softmax: row max
    const float scale = 0.125f;   // 1/sqrt(64)
    float m[2], Zi[2];
#pragma unroll
    for (int ii = 0; ii < 2; ++ii) {
        float v = acc[ii][0];
#pragma unroll
        for (int jj = 1; jj < 8; ++jj) v = fmaxf(v, acc[ii][jj]);
        v = fmaxf(v, __shfl_xor(v, 8));
        v = fmaxf(v, __shfl_xor(v, 16));
        v = fmaxf(v, __shfl_xor(v, 32));
        if ((tid & 63) < 8) redm[wv][ig * 2 + ii] = v;
    }
    __syncthreads();   // guards redm AND adj tile
#pragma unroll
    for (int ii = 0; ii < 2; ++ii) {
        int row = ig * 2 + ii;
        float v = redm[0][row];
#pragma unroll
        for (int w = 1; w < 8; ++w) v = fmaxf(v, redm[w][row]);
        m[ii] = v;
    }
    // exp + row sum
#pragma unroll
    for (int ii = 0; ii < 2; ++ii) {
        float z = 0.f;
#pragma unroll
        for (int jj = 0; jj < 8; ++jj) {
            float p = expf((acc[ii][jj] - m[ii]) * scale);
            acc[ii][jj] = p;
            z += p;
        }
        z += __shfl_xor(z, 8);
        z += __shfl_xor(z, 16);
        z += __shfl_xor(z, 32);
        if ((tid & 63) < 8) redz[wv][ig * 2 + ii] = z;
    }
    __syncthreads();
#pragma unroll
    for (int ii = 0; ii < 2; ++ii) {
        int row = ig * 2 + ii;
        float z = redz[0][row];
#pragma unroll
        for (int w = 1; w < 8; ++w) z += redz[w][row];
        Zi[ii] = 1.0f / z;
    }

    // weighting + column partial sums
    float di[2];
    di[0] = dinv[i0 + ig * 2];
    di[1] = dinv[i0 + ig * 2 + 1];
    float cs[8], cw[8];
#pragma unroll
    for (int jj = 0; jj < 8; ++jj) { cs[jj] = 0.f; cw[jj] = 0.f; }
#pragma unroll
    for (int ii = 0; ii < 2; ++ii) {
        int irow = ig * 2 + ii;
        int gi = i0 + irow;
        float av[8];
        *(float4*)&av[0] = *(const float4*)&kl[irow * 512 + jg * 8];
        *(float4*)&av[4] = *(const float4*)&kl[irow * 512 + jg * 8 + 4];
        float dz = di[ii] * Zi[ii];
#pragma unroll
        for (int jj = 0; jj < 8; ++jj) {
            int j = jg * 8 + jj;
            float a = av[jj] + (gi == j ? 1.f : 0.f);
            cs[jj] = fmaf(di[ii] * a * Zi[ii], acc[ii][jj], cs[jj]);
            cw[jj] = fmaf(di[ii], a, cw[jj]);
        }
        (void)dz;
    }
    // reduce over ig (lanes differing in bits 0..2)
#pragma unroll
    for (int jj = 0; jj < 8; ++jj) {
        float v = cs[jj];
        v += __shfl_xor(v, 1);
        v += __shfl_xor(v, 2);
        v += __shfl_xor(v, 4);
        cs[jj] = v;
    }
    if (bh == 0) {
#pragma unroll
        for (int jj = 0; jj < 8; ++jj) {
            float w = cw[jj];
            w += __shfl_xor(w, 1);
            w += __shfl_xor(w, 2);
            w += __shfl_xor(w, 4);
            cw[jj] = w;
        }
    }
    if (ig == 0) {
#pragma unroll
        for (int jj = 0; jj < 8; ++jj) {
            int j = jg * 8 + jj;
            atomicAdd(&T[bh * NN + j], cs[jj] * dinv[j]);
        }
        if (bh == 0) {
#pragma unroll
            for (int jj = 0; jj < 8; ++jj)
                atomicAdd(&cvec[jg * 8 + jj], cw[jj]);
        }
    }
}

// S3 (R4 verbatim): fused sxd + SpMM + FC + relu.
__global__ __launch_bounds__(256) void k_s3(const float* __restrict__ x,
                                            const float* __restrict__ T,
                                            const float* __restrict__ Wlin,
                                            const float* __restrict__ blin,
                                            const float* __restrict__ cvec,
                                            const float* __restrict__ adj,
                                            const float* __restrict__ dinv,
                                            const float* __restrict__ Wfc,
                                            const float* __restrict__ bfc,
                                            float* __restrict__ out) {
    __shared__ float4 u4_l[NN];
    __shared__ float  u0_l[NN];
    __shared__ float2 ad_l[NN];
    __shared__ float part[4][2][64];
    __shared__ float m_lds[2][64];
    __shared__ float part2[4][2][64];
    int blk = blockIdx.x, tid = threadIdx.x;
    int b = blk >> 8, itile = blk & 255;
    int i0 = itile * 2;

    for (int jj = tid; jj < NN; jj += 256) {
        float dj = dinv[jj];
        u0_l[jj] = dj * dj * cvec[jj];
        u4_l[jj] = make_float4(dj * T[(b * HH + 0) * NN + jj],
                               dj * T[(b * HH + 1) * NN + jj],
                               dj * T[(b * HH + 2) * NN + jj],
                               dj * T[(b * HH + 3) * NN + jj]);
        ad_l[jj] = make_float2(adj[(long)i0 * NN + jj] + (i0 == jj ? 1.f : 0.f),
                               adj[(long)(i0 + 1) * NN + jj] + (i0 + 1 == jj ? 1.f : 0.f));
    }
    __syncthreads();

    int f = tid & 63, jc = tid >> 6;
    int jb = jc * 128;
    float blf = blin[f];
    float4 wl = make_float4(Wlin[f], Wlin[64 + f], Wlin[128 + f], Wlin[192 + f]);
    const float* xb = x + (long)b * NN * FF + f;
    float a0 = 0.f, a1 = 0.f;
#pragma unroll 4
    for (int j = jb; j < jb + 128; ++j) {
        float xv = xb[(long)j * FF];
        float4 u = u4_l[j];
        float2 ad = ad_l[j];
        float S = blf * u0_l[j];
        S = fmaf(wl.x, u.x, S);
        S = fmaf(wl.y, u.y, S);
        S = fmaf(wl.z, u.z, S);
        S = fmaf(wl.w, u.w, S);
        float sx = xv * S;
        a0 = fmaf(ad.x, sx, a0);
        a1 = fmaf(ad.y, sx, a1);
    }
    part[jc][0][f] = a0;
    part[jc][1][f] = a1;
    __syncthreads();
    if (jc == 0) {
        m_lds[0][f] = (part[0][0][f] + part[1][0][f] + part[2][0][f] + part[3][0][f]) * dinv[i0];
        m_lds[1][f] = (part[0][1][f] + part[1][1][f] + part[2][1][f] + part[3][1][f]) * dinv[i0 + 1];
    }
    __syncthreads();
    float o0 = 0.f, o1 = 0.f;
    int c0 = jc * 16;
#pragma unroll
    for (int cc = 0; cc < 16; ++cc) {
        float w = Wfc[(c0 + cc) * FF + f];
        o0 = fmaf(m_lds[0][c0 + cc], w, o0);
        o1 = fmaf(m_lds[1][c0 + cc], w, o1);
    }
    part2[jc][0][f] = o0;
    part2[jc][1][f] = o1;
    __syncthreads();
    if (jc == 0) {
        float bb = bfc[f];
        float r0 = part2[0][0][f] + part2[1][0][f] + part2[2][0][f] + part2[3][0][f] + bb;
        float r1 = part2[0][1][f] + part2[1][1][f] + part2[2][1][f] + part2[3][1][f] + bb;
        out[((long)b * NN + i0) * FF + f]     = fmaxf(r0, 0.f);
        out[((long)b * NN + i0 + 1) * FF + f] = fmaxf(r1, 0.f);
    }
}

extern "C" void kernel_launch(void* const* d_in, const int* in_sizes, int n_in,
                              void* d_out, int out_size, void* d_ws, size_t ws_size,
                              hipStream_t stream) {
    const float* x    = (const float*)d_in[0];
    const float* adj  = (const float*)d_in[1];
    const float* Wq   = (const float*)d_in[2];
    const float* bq   = (const float*)d_in[3];
    const float* Wk   = (const float*)d_in[4];
    const float* bk   = (const float*)d_in[5];
    const float* Wlin = (const float*)d_in[6];
    const float* blin = (const float*)d_in[7];
    const float* Wfc  = (const float*)d_in[8];
    const float* bfc  = (const float*)d_in[9];
    float* out = (float*)d_out;

    float* ws   = (float*)d_ws;
    float* dinv = ws;                 // 512
    float* cvec = ws + 512;           // 512
    float* T    = ws + 1024;          // 8192
    float* q_t  = ws + 9216;          // 2097152
    float* k_t  = ws + 2106368;       // 2097152

    k_s1<<<dim3(1024), dim3(256), 0, stream>>>(x, Wq, bq, Wk, bk, adj, q_t, k_t, dinv, T, cvec);
    k_s2<<<dim3(512), dim3(512), 0, stream>>>(q_t, k_t, adj, dinv, T, cvec);
    k_s3<<<dim3(1024), dim3(256), 0, stream>>>(x, T, Wlin, blin, cvec, adj, dinv, Wfc, bfc, out);
}